// Round 10
// baseline (140.598 us; speedup 1.0000x reference)
//
#include <hip/hip_runtime.h>

#define NN 50000
#define NE 800000
#define DD 128

#define BK_SHIFT 8                 // bucket = row >> 8 (256 rows per bucket)
#define NBUCK 196
#define CHUNK 4096
#define NCHUNK 196                 // ceil(800000/4096)
#define NGB 782                    // ceil(50000/64) gemm blocks
#define ECAP 8192                  // entries per bucket region (mean 4096, sigma 64)

// ---------------- ws layout (float units) ----------------
#define OFF_H      0               // NN*DD bf16 = 3,200,000 floats
#define OFF_EBIN   3200000         // NBUCK*ECAP uint2 = 3,211,264 floats
#define OFF_EPACK  6411264         // NBUCK*ECAP uint2
#define OFF_END    9622528         // NN ints
#define OFF_CUR    9672528         // NBUCK ints
#define WS_FULL_FLOATS 9672724     // ~38.7 MB

typedef short short8 __attribute__((ext_vector_type(8)));
typedef float f32x4 __attribute__((ext_vector_type(4)));
typedef unsigned int uint32x2 __attribute__((ext_vector_type(2)));

static __device__ __forceinline__ unsigned int f2bf(float x) {
    unsigned int u = __float_as_uint(x);
    return (u + 0x7fffu + ((u >> 16) & 1u)) >> 16;  // RNE
}

// ============ K1: bucket-scatter (blocks 0..NCHUNK-1, first) ||
//               MFMA GEMM (blocks NCHUNK..) ============
__global__ __launch_bounds__(256) void k1_gemm_scatter(
        const float* __restrict__ seq, const float* __restrict__ W,
        unsigned short* __restrict__ h,
        const int* __restrict__ erow, const int* __restrict__ ecol,
        const float* __restrict__ eval,
        int* __restrict__ gcur, uint2* __restrict__ ebin) {
    __shared__ uint4 lds4[3072];           // 48 KB
    char* lds = (char*)lds4;
    const int t = threadIdx.x;

    if (blockIdx.x < NCHUNK) {
        // ---- scatter path: LDS hist -> global bump-reserve -> run writes ----
        int* lh = (int*)lds4;              // [NBUCK] count, then cursor
        const int chunk = blockIdx.x;
        for (int i = t; i < NBUCK; i += 256) lh[i] = 0;
        __syncthreads();
        const int e0 = chunk * CHUNK;
        for (int i = t; i < CHUNK; i += 256) {
            int e = e0 + i;
            if (e < NE) atomicAdd(&lh[erow[e] >> BK_SHIFT], 1);
        }
        __syncthreads();
        for (int i = t; i < NBUCK; i += 256) {
            int c = lh[i];
            lh[i] = c ? atomicAdd(&gcur[i], c) : 0;   // count -> bucket-local base
        }
        __syncthreads();
        for (int i = t; i < CHUNK; i += 256) {
            int e = e0 + i;
            if (e < NE) {
                int r = erow[e], c = ecol[e];
                unsigned int vb = __float_as_uint(eval[e]);
                int k = r >> BK_SHIFT;
                int pos = atomicAdd(&lh[k], 1);
                if (pos < ECAP)
                    ebin[(size_t)k * ECAP + pos] =
                        make_uint2(((unsigned)r << 16) | (unsigned)c, vb);
            }
        }
        return;
    }

    // ---- GEMM path: h[n][o] = sum_k seq[n][k]*W[o][k], bf16-in fp32-acc ----
    const int base = (blockIdx.x - NCHUNK) * 64;
#define BS_OFF 16384

    // stage Bs: W[o][k] fp32 -> bf16, swizzled. thread: o=t>>1, 64 k's.
    {
        const int o = t >> 1, ksb = (t & 1) * 64;
        const float4* Wr = (const float4*)(W + o * 128 + ksb);
#pragma unroll
        for (int i = 0; i < 16; i += 2) {
            float4 x = Wr[i], y = Wr[i + 1];
            uint4 p;
            p.x = f2bf(x.x) | (f2bf(x.y) << 16);
            p.y = f2bf(x.z) | (f2bf(x.w) << 16);
            p.z = f2bf(y.x) | (f2bf(y.y) << 16);
            p.w = f2bf(y.z) | (f2bf(y.w) << 16);
            int byte = o * 256 + (ksb + i * 4) * 2;
            *(uint4*)(lds + BS_OFF + (byte ^ ((o & 7) << 4))) = p;
        }
    }
    // stage As: seq rows [base..base+64) fp32 -> bf16, swizzled.
    {
        const int row = t >> 2, n = base + row;
        const int c0 = (t & 3) * 4;
        const float4* Sr = (const float4*)(seq + (size_t)n * 128);
        const bool ok = (n < NN);
#pragma unroll
        for (int i = 0; i < 4; ++i) {
            int cc = c0 + i;
            float4 x = ok ? Sr[cc * 2]     : make_float4(0.f, 0.f, 0.f, 0.f);
            float4 y = ok ? Sr[cc * 2 + 1] : make_float4(0.f, 0.f, 0.f, 0.f);
            uint4 p;
            p.x = f2bf(x.x) | (f2bf(x.y) << 16);
            p.y = f2bf(x.z) | (f2bf(x.w) << 16);
            p.z = f2bf(y.x) | (f2bf(y.y) << 16);
            p.w = f2bf(y.z) | (f2bf(y.w) << 16);
            int byte = row * 256 + cc * 16;
            *(uint4*)(lds + (byte ^ ((row & 7) << 4))) = p;
        }
    }
    __syncthreads();

    const int l = t & 63, wv = t >> 6;
    const int lr = l & 15, kg = l >> 4;
    const int arow = wv * 16 + lr;
    f32x4 acc[8] = {};

#pragma unroll
    for (int ks = 0; ks < 4; ++ks) {
        const int kbyte = ks * 64 + kg * 16;
        short8 av = *(short8*)(lds + ((arow * 256 + kbyte) ^ ((arow & 7) << 4)));
#pragma unroll
        for (int c = 0; c < 8; ++c) {
            const int o = c * 16 + lr;
            short8 bv = *(short8*)(lds + BS_OFF +
                                   ((o * 256 + kbyte) ^ ((o & 7) << 4)));
            acc[c] = __builtin_amdgcn_mfma_f32_16x16x32_bf16(av, bv, acc[c], 0, 0, 0);
        }
    }

#pragma unroll
    for (int c = 0; c < 8; ++c) {
#pragma unroll
        for (int r = 0; r < 4; ++r) {
            int n = base + wv * 16 + kg * 4 + r;
            if (n < NN)
                h[(size_t)n * DD + c * 16 + lr] = (unsigned short)f2bf(acc[c][r]);
        }
    }
}

// ============ K2: per-bucket CSR build + payload fill ============
__global__ __launch_bounds__(256) void csr_fill(const uint2* __restrict__ ebin,
                                                const int* __restrict__ gcur,
                                                int* __restrict__ endv,
                                                uint2* __restrict__ epack) {
    __shared__ int lh[256];
    __shared__ int lx[256];
    const int k = blockIdx.x;
    const int t = threadIdx.x;
    const size_t s0 = (size_t)k * ECAP;
    int cnt = gcur[k];
    if (cnt > ECAP) cnt = ECAP;
    const size_t s1 = s0 + cnt;
    const int r0 = k << BK_SHIFT;

    lh[t] = 0;
    __syncthreads();
    for (size_t e = s0 + t; e < s1; e += 256)
        atomicAdd(&lh[(ebin[e].x >> 16) & 255], 1);
    __syncthreads();

    const int myc = lh[t];
    lx[t] = myc;
    __syncthreads();
    for (int off = 1; off < 256; off <<= 1) {
        int y = (t >= off) ? lx[t - off] : 0;
        __syncthreads();
        lx[t] += y;
        __syncthreads();
    }
    const int incl = lx[t];
    const int row = r0 + t;
    if (row < NN) endv[row] = (int)s0 + incl;
    __syncthreads();
    lh[t] = (int)s0 + incl - myc;     // global exclusive offset (bump)
    __syncthreads();

    for (size_t e = s0 + t; e < s1; e += 256) {
        uint2 ed = ebin[e];
        int pos = atomicAdd(&lh[(ed.x >> 16) & 255], 1);
        epack[pos] = make_uint2(ed.x & 0xffffu, ed.y);
    }
}

// ============ K3: gather, wave per (row, col-quarter) ============
// quarter = blockIdx % 4 -> under round-robin block->XCD dispatch each XCD
// touches only a 3.2 MB slice of h (L2-resident). 16 edge slots x 4 lanes.
__global__ __launch_bounds__(256) void gather_kernel(const unsigned short* __restrict__ h,
                                                     const int* __restrict__ end,
                                                     const unsigned int* __restrict__ epack,
                                                     const float* __restrict__ b,
                                                     float* __restrict__ out) {
    const int q    = blockIdx.x & 3;
    const int row  = (blockIdx.x >> 2) * 4 + (threadIdx.x >> 6);
    const int lane = threadIdx.x & 63;
    const int slot = lane >> 2;      // 0..15
    const int sub  = lane & 3;       // cols q*32 + sub*8 .. +8
    const int begin = (row & 255) ? end[row - 1] : (row >> BK_SHIFT) * ECAP;
    const int e1 = end[row];

    float acc[8] = {0.f, 0.f, 0.f, 0.f, 0.f, 0.f, 0.f, 0.f};
    const unsigned short* hp = h + q * 32 + sub * 8;

#define BODY(EE) do {                                                          \
        uint32x2 cv = __builtin_nontemporal_load(                              \
            (const uint32x2*)(epack + (size_t)(EE) * 2));                      \
        float v = __uint_as_float(cv.y);                                       \
        uint4 hv = *(const uint4*)(hp + (size_t)cv.x * DD);                    \
        unsigned int uu;                                                       \
        uu = hv.x;                                                             \
        acc[0] = fmaf(v, __uint_as_float(uu << 16),          acc[0]);          \
        acc[1] = fmaf(v, __uint_as_float(uu & 0xffff0000u),  acc[1]);          \
        uu = hv.y;                                                             \
        acc[2] = fmaf(v, __uint_as_float(uu << 16),          acc[2]);          \
        acc[3] = fmaf(v, __uint_as_float(uu & 0xffff0000u),  acc[3]);          \
        uu = hv.z;                                                             \
        acc[4] = fmaf(v, __uint_as_float(uu << 16),          acc[4]);          \
        acc[5] = fmaf(v, __uint_as_float(uu & 0xffff0000u),  acc[5]);          \
        uu = hv.w;                                                             \
        acc[6] = fmaf(v, __uint_as_float(uu << 16),          acc[6]);          \
        acc[7] = fmaf(v, __uint_as_float(uu & 0xffff0000u),  acc[7]);          \
    } while (0)

    int e = begin + slot;
    for (; e + 16 < e1; e += 32) { BODY(e); BODY(e + 16); }
    if (e < e1) BODY(e);
#undef BODY

#pragma unroll
    for (int i = 0; i < 8; ++i) {
        acc[i] += __shfl_xor(acc[i], 4);
        acc[i] += __shfl_xor(acc[i], 8);
        acc[i] += __shfl_xor(acc[i], 16);
        acc[i] += __shfl_xor(acc[i], 32);
    }

    if (slot == 0) {
        const float4* b4 = (const float4*)(b + q * 32 + sub * 8);
        float4 b0 = b4[0], b1 = b4[1];
        f32x4 o0, o1;
        o0.x = fmaxf(acc[0] + b0.x, 0.f);
        o0.y = fmaxf(acc[1] + b0.y, 0.f);
        o0.z = fmaxf(acc[2] + b0.z, 0.f);
        o0.w = fmaxf(acc[3] + b0.w, 0.f);
        o1.x = fmaxf(acc[4] + b1.x, 0.f);
        o1.y = fmaxf(acc[5] + b1.y, 0.f);
        o1.z = fmaxf(acc[6] + b1.z, 0.f);
        o1.w = fmaxf(acc[7] + b1.w, 0.f);
        f32x4* op = (f32x4*)(out + (size_t)row * DD + q * 32 + sub * 8);
        __builtin_nontemporal_store(o0, op);
        __builtin_nontemporal_store(o1, op + 1);
    }
}

// ============ Fallback (ws too small): atomic scatter path ============
__global__ __launch_bounds__(256) void scatter_kernel(const unsigned short* __restrict__ h,
                                                      const int* __restrict__ erow,
                                                      const int* __restrict__ ecol,
                                                      const float* __restrict__ eval,
                                                      float* __restrict__ out) {
    const int lane   = threadIdx.x & 63;
    const int wave   = (blockIdx.x * blockDim.x + threadIdx.x) >> 6;
    const int nwaves = (gridDim.x * blockDim.x) >> 6;
    for (int e = wave; e < NE; e += nwaves) {
        int   r = erow[e];
        int   c = ecol[e];
        float v = eval[e];
        unsigned int u = *(const unsigned int*)&h[(size_t)c * DD + lane * 2];
        float* dst = &out[(size_t)r * DD + lane * 2];
        unsafeAtomicAdd(dst,     __uint_as_float(u << 16) * v);
        unsafeAtomicAdd(dst + 1, __uint_as_float(u & 0xffff0000u) * v);
    }
}

__global__ __launch_bounds__(256) void epilogue_kernel(float* __restrict__ out,
                                                       const float* __restrict__ b) {
    const float4* b4 = (const float4*)b;
    const int total4 = NN * DD / 4;
    int i = blockIdx.x * blockDim.x + threadIdx.x;
    for (; i < total4; i += gridDim.x * blockDim.x) {
        float4 x = ((float4*)out)[i];
        float4 bb = b4[i & 31];
        x.x = fmaxf(x.x + bb.x, 0.0f);
        x.y = fmaxf(x.y + bb.y, 0.0f);
        x.z = fmaxf(x.z + bb.z, 0.0f);
        x.w = fmaxf(x.w + bb.w, 0.0f);
        ((float4*)out)[i] = x;
    }
}

extern "C" void kernel_launch(void* const* d_in, const int* in_sizes, int n_in,
                              void* d_out, int out_size, void* d_ws, size_t ws_size,
                              hipStream_t stream) {
    const float* seq  = (const float*)d_in[0];
    const float* W    = (const float*)d_in[1];
    const float* b    = (const float*)d_in[2];
    const int*   erow = (const int*)d_in[3];
    const int*   ecol = (const int*)d_in[4];
    const float* eval = (const float*)d_in[5];
    float* out = (float*)d_out;

    float* wsf = (float*)d_ws;
    unsigned short* h = (unsigned short*)(wsf + OFF_H);
    uint2* ebin  = (uint2*)(wsf + OFF_EBIN);
    uint2* epack = (uint2*)(wsf + OFF_EPACK);
    int*   endv  = (int*)(wsf + OFF_END);
    int*   gcur  = (int*)(wsf + OFF_CUR);

    if (ws_size >= (size_t)WS_FULL_FLOATS * sizeof(float)) {
        hipMemsetAsync(gcur, 0, NBUCK * sizeof(int), stream);
        k1_gemm_scatter<<<NGB + NCHUNK, 256, 0, stream>>>(seq, W, h, erow, ecol,
                                                          eval, gcur, ebin);
        csr_fill<<<NBUCK, 256, 0, stream>>>(ebin, gcur, endv, epack);
        gather_kernel<<<NN, 256, 0, stream>>>(h, endv, (const unsigned int*)epack, b, out);
    } else {
        k1_gemm_scatter<<<NGB + NCHUNK, 256, 0, stream>>>(seq, W, h, erow, ecol,
                                                          eval, gcur, ebin);
        hipMemsetAsync(out, 0, (size_t)out_size * sizeof(float), stream);
        scatter_kernel<<<4096, 256, 0, stream>>>(h, erow, ecol, eval, out);
        epilogue_kernel<<<2048, 256, 0, stream>>>(out, b);
    }
}

// Round 11
// 85.132 us; speedup vs baseline: 1.6515x; 1.6515x over previous
//
#include <hip/hip_runtime.h>

#define NN 50000
#define NE 800000
#define DD 128

#define BK_SHIFT 8                 // bucket = row >> 8 (256 rows per bucket)
#define NBUCK 196
#define CHUNK 2048
#define NCHUNK 391                 // ceil(800000/2048)
#define NGB 782                    // ceil(50000/64) gemm blocks
#define ECAP 8192                  // entries per bucket region (mean 4096, sigma 64)

// ---------------- ws layout (float units) ----------------
#define OFF_H      0               // NN*DD bf16 = 3,200,000 floats
#define OFF_EBIN   3200000         // NBUCK*ECAP uint2 = 3,211,264 floats
#define OFF_EPACK  6411264         // NBUCK*ECAP uint2
#define OFF_END    9622528         // NN ints
#define OFF_CUR    9672528         // NBUCK ints
#define WS_FULL_FLOATS 9672724     // ~38.7 MB

typedef short short8 __attribute__((ext_vector_type(8)));
typedef float f32x4 __attribute__((ext_vector_type(4)));
typedef unsigned int uint32x2 __attribute__((ext_vector_type(2)));

static __device__ __forceinline__ unsigned int f2bf(float x) {
    unsigned int u = __float_as_uint(x);
    return (u + 0x7fffu + ((u >> 16) & 1u)) >> 16;  // RNE
}

// ============ K1: bucket-scatter (blocks 0..NCHUNK-1, first) ||
//               MFMA GEMM (blocks NCHUNK..) ============
__global__ __launch_bounds__(256) void k1_gemm_scatter(
        const float* __restrict__ seq, const float* __restrict__ W,
        unsigned short* __restrict__ h,
        const int* __restrict__ erow, const int* __restrict__ ecol,
        const float* __restrict__ eval,
        int* __restrict__ gcur, uint2* __restrict__ ebin) {
    __shared__ uint4 lds4[3072];           // 48 KB
    char* lds = (char*)lds4;
    const int t = threadIdx.x;

    if (blockIdx.x < NCHUNK) {
        // ---- scatter path: LDS hist -> global bump-reserve -> run writes ----
        int* lh = (int*)lds4;              // [NBUCK] count, then cursor
        const int chunk = blockIdx.x;
        for (int i = t; i < NBUCK; i += 256) lh[i] = 0;
        __syncthreads();
        const int e0 = chunk * CHUNK;
        for (int i = t; i < CHUNK; i += 256) {
            int e = e0 + i;
            if (e < NE) atomicAdd(&lh[erow[e] >> BK_SHIFT], 1);
        }
        __syncthreads();
        for (int i = t; i < NBUCK; i += 256) {
            int c = lh[i];
            lh[i] = c ? atomicAdd(&gcur[i], c) : 0;   // count -> bucket-local base
        }
        __syncthreads();
        for (int i = t; i < CHUNK; i += 256) {
            int e = e0 + i;
            if (e < NE) {
                int r = erow[e], c = ecol[e];
                unsigned int vb = __float_as_uint(eval[e]);
                int k = r >> BK_SHIFT;
                int pos = atomicAdd(&lh[k], 1);
                if (pos < ECAP)
                    ebin[(size_t)k * ECAP + pos] =
                        make_uint2(((unsigned)r << 16) | (unsigned)c, vb);
            }
        }
        return;
    }

    // ---- GEMM path: h[n][o] = sum_k seq[n][k]*W[o][k], bf16-in fp32-acc ----
    const int base = (blockIdx.x - NCHUNK) * 64;
#define BS_OFF 16384

    // stage Bs: W[o][k] fp32 -> bf16, swizzled. thread: o=t>>1, 64 k's.
    {
        const int o = t >> 1, ksb = (t & 1) * 64;
        const float4* Wr = (const float4*)(W + o * 128 + ksb);
#pragma unroll
        for (int i = 0; i < 16; i += 2) {
            float4 x = Wr[i], y = Wr[i + 1];
            uint4 p;
            p.x = f2bf(x.x) | (f2bf(x.y) << 16);
            p.y = f2bf(x.z) | (f2bf(x.w) << 16);
            p.z = f2bf(y.x) | (f2bf(y.y) << 16);
            p.w = f2bf(y.z) | (f2bf(y.w) << 16);
            int byte = o * 256 + (ksb + i * 4) * 2;
            *(uint4*)(lds + BS_OFF + (byte ^ ((o & 7) << 4))) = p;
        }
    }
    // stage As: seq rows [base..base+64) fp32 -> bf16, swizzled.
    {
        const int row = t >> 2, n = base + row;
        const int c0 = (t & 3) * 4;
        const float4* Sr = (const float4*)(seq + (size_t)n * 128);
        const bool ok = (n < NN);
#pragma unroll
        for (int i = 0; i < 4; ++i) {
            int cc = c0 + i;
            float4 x = ok ? Sr[cc * 2]     : make_float4(0.f, 0.f, 0.f, 0.f);
            float4 y = ok ? Sr[cc * 2 + 1] : make_float4(0.f, 0.f, 0.f, 0.f);
            uint4 p;
            p.x = f2bf(x.x) | (f2bf(x.y) << 16);
            p.y = f2bf(x.z) | (f2bf(x.w) << 16);
            p.z = f2bf(y.x) | (f2bf(y.y) << 16);
            p.w = f2bf(y.z) | (f2bf(y.w) << 16);
            int byte = row * 256 + cc * 16;
            *(uint4*)(lds + (byte ^ ((row & 7) << 4))) = p;
        }
    }
    __syncthreads();

    const int l = t & 63, wv = t >> 6;
    const int lr = l & 15, kg = l >> 4;
    const int arow = wv * 16 + lr;
    f32x4 acc[8] = {};

#pragma unroll
    for (int ks = 0; ks < 4; ++ks) {
        const int kbyte = ks * 64 + kg * 16;
        short8 av = *(short8*)(lds + ((arow * 256 + kbyte) ^ ((arow & 7) << 4)));
#pragma unroll
        for (int c = 0; c < 8; ++c) {
            const int o = c * 16 + lr;
            short8 bv = *(short8*)(lds + BS_OFF +
                                   ((o * 256 + kbyte) ^ ((o & 7) << 4)));
            acc[c] = __builtin_amdgcn_mfma_f32_16x16x32_bf16(av, bv, acc[c], 0, 0, 0);
        }
    }

#pragma unroll
    for (int c = 0; c < 8; ++c) {
#pragma unroll
        for (int r = 0; r < 4; ++r) {
            int n = base + wv * 16 + kg * 4 + r;
            if (n < NN)
                h[(size_t)n * DD + c * 16 + lr] = (unsigned short)f2bf(acc[c][r]);
        }
    }
}

// ============ K2: per-bucket CSR build + payload fill ============
__global__ __launch_bounds__(256) void csr_fill(const uint2* __restrict__ ebin,
                                                const int* __restrict__ gcur,
                                                int* __restrict__ endv,
                                                uint2* __restrict__ epack) {
    __shared__ int lh[256];
    __shared__ int lx[256];
    const int k = blockIdx.x;
    const int t = threadIdx.x;
    const size_t s0 = (size_t)k * ECAP;
    int cnt = gcur[k];
    if (cnt > ECAP) cnt = ECAP;
    const size_t s1 = s0 + cnt;
    const int r0 = k << BK_SHIFT;

    lh[t] = 0;
    __syncthreads();
    for (size_t e = s0 + t; e < s1; e += 256)
        atomicAdd(&lh[(ebin[e].x >> 16) & 255], 1);
    __syncthreads();

    const int myc = lh[t];
    lx[t] = myc;
    __syncthreads();
    for (int off = 1; off < 256; off <<= 1) {
        int y = (t >= off) ? lx[t - off] : 0;
        __syncthreads();
        lx[t] += y;
        __syncthreads();
    }
    const int incl = lx[t];
    const int row = r0 + t;
    if (row < NN) endv[row] = (int)s0 + incl;
    __syncthreads();
    lh[t] = (int)s0 + incl - myc;     // global exclusive offset (bump)
    __syncthreads();

    for (size_t e = s0 + t; e < s1; e += 256) {
        uint2 ed = ebin[e];
        int pos = atomicAdd(&lh[(ed.x >> 16) & 255], 1);
        epack[pos] = make_uint2(ed.x & 0xffffu, ed.y);
    }
}

// ============ K3: gather, wave per row, 4 edge slots x 16 lanes, 4-deep MLP ==
__global__ __launch_bounds__(256) void gather_kernel(const unsigned short* __restrict__ h,
                                                     const int* __restrict__ end,
                                                     const unsigned int* __restrict__ epack,
                                                     const float* __restrict__ b,
                                                     float* __restrict__ out) {
    const int row  = blockIdx.x * 4 + (threadIdx.x >> 6);
    const int lane = threadIdx.x & 63;
    const int slot = lane >> 4;
    const int sub  = lane & 15;
    const int begin = (row & 255) ? end[row - 1] : (row >> BK_SHIFT) * ECAP;
    const int e1 = end[row];

    float acc[8] = {0.f, 0.f, 0.f, 0.f, 0.f, 0.f, 0.f, 0.f};
    const unsigned short* hp = h + sub * 8;

#define BODY(EE) do {                                                          \
        uint32x2 cv = __builtin_nontemporal_load(                              \
            (const uint32x2*)(epack + (size_t)(EE) * 2));                      \
        float v = __uint_as_float(cv.y);                                       \
        uint4 hv = *(const uint4*)(hp + (size_t)cv.x * DD);                    \
        unsigned int uu;                                                       \
        uu = hv.x;                                                             \
        acc[0] = fmaf(v, __uint_as_float(uu << 16),          acc[0]);          \
        acc[1] = fmaf(v, __uint_as_float(uu & 0xffff0000u),  acc[1]);          \
        uu = hv.y;                                                             \
        acc[2] = fmaf(v, __uint_as_float(uu << 16),          acc[2]);          \
        acc[3] = fmaf(v, __uint_as_float(uu & 0xffff0000u),  acc[3]);          \
        uu = hv.z;                                                             \
        acc[4] = fmaf(v, __uint_as_float(uu << 16),          acc[4]);          \
        acc[5] = fmaf(v, __uint_as_float(uu & 0xffff0000u),  acc[5]);          \
        uu = hv.w;                                                             \
        acc[6] = fmaf(v, __uint_as_float(uu << 16),          acc[6]);          \
        acc[7] = fmaf(v, __uint_as_float(uu & 0xffff0000u),  acc[7]);          \
    } while (0)

    int e = begin + slot;
    for (; e + 12 < e1; e += 16) { BODY(e); BODY(e + 4); BODY(e + 8); BODY(e + 12); }
    for (; e < e1; e += 4) BODY(e);
#undef BODY

#pragma unroll
    for (int i = 0; i < 8; ++i) {
        acc[i] += __shfl_xor(acc[i], 16);
        acc[i] += __shfl_xor(acc[i], 32);
    }

    if (slot == 0) {
        const float4* b4 = (const float4*)(b + sub * 8);
        float4 b0 = b4[0], b1 = b4[1];
        f32x4 o0, o1;
        o0.x = fmaxf(acc[0] + b0.x, 0.f);
        o0.y = fmaxf(acc[1] + b0.y, 0.f);
        o0.z = fmaxf(acc[2] + b0.z, 0.f);
        o0.w = fmaxf(acc[3] + b0.w, 0.f);
        o1.x = fmaxf(acc[4] + b1.x, 0.f);
        o1.y = fmaxf(acc[5] + b1.y, 0.f);
        o1.z = fmaxf(acc[6] + b1.z, 0.f);
        o1.w = fmaxf(acc[7] + b1.w, 0.f);
        f32x4* op = (f32x4*)(out + (size_t)row * DD + sub * 8);
        __builtin_nontemporal_store(o0, op);
        __builtin_nontemporal_store(o1, op + 1);
    }
}

// ============ Fallback (ws too small): atomic scatter path ============
__global__ __launch_bounds__(256) void scatter_kernel(const unsigned short* __restrict__ h,
                                                      const int* __restrict__ erow,
                                                      const int* __restrict__ ecol,
                                                      const float* __restrict__ eval,
                                                      float* __restrict__ out) {
    const int lane   = threadIdx.x & 63;
    const int wave   = (blockIdx.x * blockDim.x + threadIdx.x) >> 6;
    const int nwaves = (gridDim.x * blockDim.x) >> 6;
    for (int e = wave; e < NE; e += nwaves) {
        int   r = erow[e];
        int   c = ecol[e];
        float v = eval[e];
        unsigned int u = *(const unsigned int*)&h[(size_t)c * DD + lane * 2];
        float* dst = &out[(size_t)r * DD + lane * 2];
        unsafeAtomicAdd(dst,     __uint_as_float(u << 16) * v);
        unsafeAtomicAdd(dst + 1, __uint_as_float(u & 0xffff0000u) * v);
    }
}

__global__ __launch_bounds__(256) void epilogue_kernel(float* __restrict__ out,
                                                       const float* __restrict__ b) {
    const float4* b4 = (const float4*)b;
    const int total4 = NN * DD / 4;
    int i = blockIdx.x * blockDim.x + threadIdx.x;
    for (; i < total4; i += gridDim.x * blockDim.x) {
        float4 x = ((float4*)out)[i];
        float4 bb = b4[i & 31];
        x.x = fmaxf(x.x + bb.x, 0.0f);
        x.y = fmaxf(x.y + bb.y, 0.0f);
        x.z = fmaxf(x.z + bb.z, 0.0f);
        x.w = fmaxf(x.w + bb.w, 0.0f);
        ((float4*)out)[i] = x;
    }
}

extern "C" void kernel_launch(void* const* d_in, const int* in_sizes, int n_in,
                              void* d_out, int out_size, void* d_ws, size_t ws_size,
                              hipStream_t stream) {
    const float* seq  = (const float*)d_in[0];
    const float* W    = (const float*)d_in[1];
    const float* b    = (const float*)d_in[2];
    const int*   erow = (const int*)d_in[3];
    const int*   ecol = (const int*)d_in[4];
    const float* eval = (const float*)d_in[5];
    float* out = (float*)d_out;

    float* wsf = (float*)d_ws;
    unsigned short* h = (unsigned short*)(wsf + OFF_H);
    uint2* ebin  = (uint2*)(wsf + OFF_EBIN);
    uint2* epack = (uint2*)(wsf + OFF_EPACK);
    int*   endv  = (int*)(wsf + OFF_END);
    int*   gcur  = (int*)(wsf + OFF_CUR);

    if (ws_size >= (size_t)WS_FULL_FLOATS * sizeof(float)) {
        hipMemsetAsync(gcur, 0, NBUCK * sizeof(int), stream);
        k1_gemm_scatter<<<NGB + NCHUNK, 256, 0, stream>>>(seq, W, h, erow, ecol,
                                                          eval, gcur, ebin);
        csr_fill<<<NBUCK, 256, 0, stream>>>(ebin, gcur, endv, epack);
        gather_kernel<<<NN / 4, 256, 0, stream>>>(h, endv, (const unsigned int*)epack, b, out);
    } else {
        k1_gemm_scatter<<<NGB + NCHUNK, 256, 0, stream>>>(seq, W, h, erow, ecol,
                                                          eval, gcur, ebin);
        hipMemsetAsync(out, 0, (size_t)out_size * sizeof(float), stream);
        scatter_kernel<<<4096, 256, 0, stream>>>(h, erow, ecol, eval, out);
        epilogue_kernel<<<2048, 256, 0, stream>>>(out, b);
    }
}